// Round 14
// baseline (187.523 us; speedup 1.0000x reference)
//
#include <hip/hip_runtime.h>
#include <math.h>

#define NB 4
#define NL 576
#define NC 256
#define NTOK (NB*NL)      // 2304
#define NDIN 512
#define NXD 112
#define NDTR 16
#define NDST 48
#define NFREQ 289
#define NWIN 1024
#define NMROW (NB*NFREQ)  // 1156
#define NKPK 608          // packed K for irfft (2*289 -> 608)

// ---- workspace layout (f32-equivalent offsets) ----
#define OFF_HB    0u          // hb bf16 [2304][256] (reused as h2b)
#define OFF_XRF   147456u     // xr f32 [2304][1024]
#define OFF_XCT   2506752u    // xc_t f32 [512][2304]
#define OFF_REST  3686400u    // res_t f32 [512][2304]
#define OFF_XCB   4866048u    // xcb bf16 [2304][512]
#define OFF_XDBL  5455872u    // xdbl packed u32: dtP [8][2304] + bcP [48][2304]
#define OFF_YFT   5584896u    // yf_t f32 [512][2304] -> PK bf16 [2048][608] later
#define OFF_X2    6764544u    // x2 f32 [2304][256]
#define OFF_FTB   7354368u    // ftb bf16 [512][2304]
#define OFF_RF    7944192u    // RFb bf16 [1156][512]
#define OFF_IF    8240128u    // IFb bf16
#define OFF_YFB   8536064u    // yfb bf16 [2304][512]
#define OFF_FFB   9125888u    // ffb bf16 [2304][512]
#define OFF_WINT  9715712u    // winT bf16 [1024][256]
#define OFF_WRT   9846784u    // Wrt bf16 [512][512]
#define OFF_WIT   9977856u    // Wit bf16 [512][512]
#define OFF_WXPT  10108928u   // wxpT bf16 [112][512]
#define OFF_WOT   10137600u   // woT bf16 [256][512]
#define OFF_FC1T  10203136u   // fc1T bf16 [512][256]
#define OFF_FC2T  10268672u   // fc2T bf16 [256][512]
#define OFF_CF    10334208u   // Cfb bf16 [320][576]
#define OFF_SF    10426368u   // Sfb bf16 [320][576]
#define OFF_CI    10518528u   // Cib bf16 [576][608]   end 10693632

typedef __attribute__((ext_vector_type(8))) short bf16x8;
typedef __attribute__((ext_vector_type(4))) float f32x4;
typedef __attribute__((ext_vector_type(4))) int   i32x4;

__device__ __forceinline__ float wave_sum(float v) {
#pragma unroll
  for (int o = 32; o > 0; o >>= 1) v += __shfl_xor(v, o);
  return v;
}

__device__ __forceinline__ unsigned short f2bf(float f) {
  unsigned int u = __float_as_uint(f);
  unsigned int r = (u + 0x7fffu + ((u >> 16) & 1u)) >> 16;  // RNE
  return (unsigned short)r;
}
__device__ __forceinline__ float b2f(unsigned short u) {
  return __uint_as_float(((unsigned int)u) << 16);
}

// 64-lane inclusive prefix sum via DPP + readlane broadcasts.
__device__ __forceinline__ float wave_iscan(float x, int lane) {
  x += __int_as_float(__builtin_amdgcn_update_dpp(0, __float_as_int(x), 0x111, 0xf, 0xf, true));
  x += __int_as_float(__builtin_amdgcn_update_dpp(0, __float_as_int(x), 0x112, 0xf, 0xf, true));
  x += __int_as_float(__builtin_amdgcn_update_dpp(0, __float_as_int(x), 0x114, 0xf, 0xf, true));
  x += __int_as_float(__builtin_amdgcn_update_dpp(0, __float_as_int(x), 0x118, 0xf, 0xf, true));
  int xi = __float_as_int(x);
  float s15 = __int_as_float(__builtin_amdgcn_readlane(xi, 15));
  float s31 = __int_as_float(__builtin_amdgcn_readlane(xi, 31));
  float s47 = __int_as_float(__builtin_amdgcn_readlane(xi, 47));
  float off = 0.f;
  if (lane >= 16) off += s15;
  if (lane >= 32) off += s31;
  if (lane >= 48) off += s47;
  return x + off;
}

// device-side 64x64 transpose+bf16 pack tile
__device__ void packT_dev(const float* __restrict__ src, unsigned short* __restrict__ dst,
                          int R, int C, int tile, int cblks) {
  __shared__ float t[64][65];
  int cb = tile % cblks, rb = tile / cblks;
  int c0 = cb * 64, r0 = rb * 64;
  int tid = threadIdx.x;
  for (int u = tid; u < 4096; u += 256) {
    int r = u >> 6, c = u & 63;
    float v = 0.f;
    if (r0 + r < R && c0 + c < C) v = src[(size_t)(r0 + r) * C + c0 + c];
    t[r][c] = v;
  }
  __syncthreads();
  for (int u = tid; u < 4096; u += 256) {
    int nr = u >> 6, nc = u & 63;
    if (c0 + nr < C && r0 + nc < R)
      dst[(size_t)(c0 + nr) * R + r0 + nc] = f2bf(t[nc][nr]);
  }
}

// double LayerNorm over one row (wave-level), bf16 out.
__device__ void ln_row2(const float* __restrict__ in, unsigned short* __restrict__ out,
                        const float* __restrict__ g1, const float* __restrict__ b1,
                        const float* __restrict__ g2, const float* __restrict__ b2,
                        int row, int lane) {
  const float* p = in + (size_t)row * NC;
  float v[4];
#pragma unroll
  for (int j = 0; j < 4; ++j) v[j] = p[lane + j * 64];
  float s = wave_sum(v[0] + v[1] + v[2] + v[3]);
  float m = s * (1.f / NC);
  float q = 0.f;
#pragma unroll
  for (int j = 0; j < 4; ++j) { float dd = v[j] - m; q += dd * dd; }
  q = wave_sum(q);
  float rs = 1.f / sqrtf(q * (1.f / NC) + 1e-3f);
#pragma unroll
  for (int j = 0; j < 4; ++j) {
    int c = lane + j * 64;
    v[j] = (v[j] - m) * rs * g1[c] + b1[c];
  }
  s = wave_sum(v[0] + v[1] + v[2] + v[3]);
  m = s * (1.f / NC);
  q = 0.f;
#pragma unroll
  for (int j = 0; j < 4; ++j) { float dd = v[j] - m; q += dd * dd; }
  q = wave_sum(q);
  rs = 1.f / sqrtf(q * (1.f / NC) + 1e-3f);
  unsigned short* o = out + (size_t)row * NC;
#pragma unroll
  for (int j = 0; j < 4; ++j) {
    int c = lane + j * 64;
    o[c] = f2bf((v[j] - m) * rs * g2[c] + b2[c]);
  }
}

// ONE setup kernel: all weight packs + trig matrices + first double-LN.
__global__ __launch_bounds__(256) void setup_kernel(
    const float* __restrict__ w_in, const float* __restrict__ Wr,
    const float* __restrict__ Wi, const float* __restrict__ wxp,
    const float* __restrict__ wo, const float* __restrict__ fc1,
    const float* __restrict__ fc2,
    unsigned short* __restrict__ winT, unsigned short* __restrict__ Wrt,
    unsigned short* __restrict__ Wit, unsigned short* __restrict__ wxpT,
    unsigned short* __restrict__ woT, unsigned short* __restrict__ fc1T,
    unsigned short* __restrict__ fc2T, unsigned short* __restrict__ Cf,
    unsigned short* __restrict__ Sf, unsigned short* __restrict__ Ci,
    const float* __restrict__ x, unsigned short* __restrict__ hb,
    const float* __restrict__ ln1_g, const float* __restrict__ ln1_b,
    const float* __restrict__ mln_g, const float* __restrict__ mln_b) {
  int bid = blockIdx.x;
  const float TWO_PI_N = 6.28318530717958647692f / (float)NL;
  if (bid < 64)       packT_dev(w_in, winT, NC, NWIN, bid, 16);
  else if (bid < 128) packT_dev(Wr, Wrt, NDIN, NDIN, bid - 64, 8);
  else if (bid < 192) packT_dev(Wi, Wit, NDIN, NDIN, bid - 128, 8);
  else if (bid < 208) packT_dev(wxp, wxpT, NDIN, NXD, bid - 192, 2);
  else if (bid < 240) packT_dev(wo, woT, NDIN, NC, bid - 208, 4);
  else if (bid < 272) packT_dev(fc1, fc1T, NC, NDIN, bid - 240, 8);
  else if (bid < 304) packT_dev(fc2, fc2T, NDIN, NC, bid - 272, 4);
  else if (bid < 384) {            // Cf/Sf: 80 blocks x 4 m-rows
    int m0 = (bid - 304) * 4;
    for (int u = threadIdx.x; u < 4 * NL; u += 256) {
      int m = m0 + u / NL, l = u % NL;
      float c = 0.f, s = 0.f;
      if (m < NFREQ) {
        int idx = (m * l) % NL;
        float sv, cv;
        __sincosf(TWO_PI_N * idx, &sv, &cv);
        c = cv * (1.f / 24.f);
        s = -sv * (1.f / 24.f);
      }
      Cf[(size_t)m * NL + l] = f2bf(c);
      Sf[(size_t)m * NL + l] = f2bf(s);
    }
  } else if (bid < 456) {          // Ci: 72 blocks x 8 l-rows
    int l0 = (bid - 384) * 8;
    for (int u = threadIdx.x; u < 8 * NKPK; u += 256) {
      int l = l0 + u / NKPK, k = u % NKPK;
      float v = 0.f;
      if (k < NFREQ) {
        float w = (k == 0 || k == NFREQ - 1) ? 1.f : 2.f;
        int idx = (k * l) % NL;
        float sv, cv;
        __sincosf(TWO_PI_N * idx, &sv, &cv);
        v = w * cv * (1.f / 24.f);
      } else if (k < 2 * NFREQ) {
        int kk = k - NFREQ;
        float w = (kk == 0 || kk == NFREQ - 1) ? 1.f : 2.f;
        int idx = (kk * l) % NL;
        float sv, cv;
        __sincosf(TWO_PI_N * idx, &sv, &cv);
        v = -w * sv * (1.f / 24.f);
      }
      Ci[(size_t)l * NKPK + k] = f2bf(v);
    }
  } else {                         // ln1: 576 blocks x 4 rows (wave per row)
    int row = (bid - 456) * 4 + (threadIdx.x >> 6);
    ln_row2(x, hb, ln1_g, ln1_b, mln_g, mln_b, row, threadIdx.x & 63);
  }
}

// one wave per token row; bf16 output (single LN).
__global__ void ln_kernel(const float* __restrict__ in, unsigned short* __restrict__ out,
                          const float* __restrict__ g1, const float* __restrict__ b1) {
  int row = blockIdx.x, lane = threadIdx.x;
  const float* p = in + (size_t)row * NC;
  float v[4];
#pragma unroll
  for (int j = 0; j < 4; ++j) v[j] = p[lane + j * 64];
  float s = wave_sum(v[0] + v[1] + v[2] + v[3]);
  float m = s * (1.f / NC);
  float q = 0.f;
#pragma unroll
  for (int j = 0; j < 4; ++j) { float d = v[j] - m; q += d * d; }
  q = wave_sum(q);
  float rs = 1.f / sqrtf(q * (1.f / NC) + 1e-3f);
  unsigned short* o = out + (size_t)row * NC;
#pragma unroll
  for (int j = 0; j < 4; ++j) {
    int c = lane + j * 64;
    o[c] = f2bf((v[j] - m) * rs * g1[c] + b1[c]);
  }
}

// standalone transpose+bf16 pack (for yf_t -> yfb)
__global__ __launch_bounds__(256) void packT_kernel(
    const float* __restrict__ src, unsigned short* __restrict__ dst, int R, int C) {
  packT_dev(src, dst, R, C, blockIdx.y * gridDim.x + blockIdx.x, gridDim.x);
}

// generic MFMA GEMM: C = A[M][K]bf16 @ B[N][K]bf16^T (f32 accum), fused epilogues.
// mode 0: store; 2: v+add; 3: relu(v*scl+bias); 4: v*scl+bias+add
// flags bit1: transposed store C[n][m]; bit2: bf16 store;
// flags bit3: scan-permute token index on transposed store;
// flags bit4: scan-PACKED store (dt pairs + B/C pairs, token-permuted).
__global__ __launch_bounds__(256) void gemm_mfma(
    const unsigned short* __restrict__ A, const unsigned short* __restrict__ B,
    void* __restrict__ C, int ldc, int M, int N, int K, int mode, int flags,
    const float* __restrict__ scl, const float* __restrict__ bias,
    const float* __restrict__ add, int ldadd) {
  __shared__ unsigned short As[64][40], Bs[64][40];
  int tid = threadIdx.x, lane = tid & 63, wv = tid >> 6;
  int n0 = blockIdx.x * 64, m0 = blockIdx.y * 64;
  int sm = tid >> 2, part = tid & 3;
  f32x4 acc[4] = {};
  for (int k0 = 0; k0 < K; k0 += 32) {
    *(bf16x8*)&As[sm][part * 8] = *(const bf16x8*)(A + (size_t)(m0 + sm) * K + k0 + part * 8);
    bf16x8 bv = {};
    if (n0 + sm < N) bv = *(const bf16x8*)(B + (size_t)(n0 + sm) * K + k0 + part * 8);
    *(bf16x8*)&Bs[sm][part * 8] = bv;
    __syncthreads();
    int am = wv * 16 + (lane & 15), koff = (lane >> 4) * 8;
    bf16x8 a = *(bf16x8*)&As[am][koff];
#pragma unroll
    for (int t = 0; t < 4; ++t) {
      bf16x8 b = *(bf16x8*)&Bs[t * 16 + (lane & 15)][koff];
      acc[t] = __builtin_amdgcn_mfma_f32_16x16x32_bf16(a, b, acc[t], 0, 0, 0);
    }
    __syncthreads();
  }
#pragma unroll
  for (int t = 0; t < 4; ++t) {
    int gn = n0 + t * 16 + (lane & 15);
    if (gn >= N) continue;
    float sv = scl ? scl[gn] : 0.f, bvv = bias ? bias[gn] : 0.f;
#pragma unroll
    for (int r = 0; r < 4; ++r) {
      int gm = m0 + wv * 16 + (lane >> 4) * 4 + r;
      float v = acc[t][r];
      if (mode == 2) v += add[(size_t)gm * ldadd + gn];
      else if (mode == 3) v = fmaxf(v * sv + bvv, 0.f);
      else if (mode == 4) v = v * sv + bvv + add[(size_t)gm * ldadd + gn];
      if (flags & 16) {
        int bq = gm / NL, tt = gm - bq * NL;
        int t9 = tt / 9;
        int pt = bq * NL + (tt - t9 * 9) * 64 + t9;
        unsigned short* D = (unsigned short*)C;
        size_t idx;
        if (gn < NDTR) idx = (((size_t)(gn >> 1)) * NTOK + pt) * 2 + (gn & 1);
        else if (gn < NDTR + NDST) idx = (size_t)16 * NTOK + ((size_t)(gn - NDTR) * NTOK + pt) * 2;
        else idx = (size_t)16 * NTOK + ((size_t)(gn - NDTR - NDST) * NTOK + pt) * 2 + 1;
        D[idx] = f2bf(v);
        continue;
      }
      int gms = gm;
      if (flags & 8) {
        int bq = gm / NL, tt = gm - bq * NL;
        int t9 = tt / 9;
        gms = bq * NL + (tt - t9 * 9) * 64 + t9;
      }
      size_t o = (flags & 2) ? (size_t)gn * ldc + gms : (size_t)gm * ldc + gn;
      if (flags & 4) ((unsigned short*)C)[o] = f2bf(v);
      else ((float*)C)[o] = v;
    }
  }
}

// Fused causal depthwise conv(4)+silu: xc_t f32 (d-major) + xcb bf16 (tok-major);
// z=1: res transpose -> res_t.
__global__ __launch_bounds__(256) void convT_kernel(
    const float* __restrict__ xr, const float* __restrict__ cw,
    const float* __restrict__ cb, float* __restrict__ xc_t,
    float* __restrict__ res_t, unsigned short* __restrict__ xcb) {
  __shared__ float tile[67][65];
  int d0 = blockIdx.x * 64;
  int rt = blockIdx.y;
  int b = rt / 9, l0 = (rt % 9) * 64;
  int tid = threadIdx.x;
  int li = tid & 63, dj0 = tid >> 6;
  if (blockIdx.z == 0) {
    for (int u = tid; u < 67 * 16; u += 256) {
      int r = u >> 4, c4 = (u & 15) * 4;
      int l = l0 - 3 + r;
      float4 v = make_float4(0.f, 0.f, 0.f, 0.f);
      if (l >= 0) v = *reinterpret_cast<const float4*>(xr + (size_t)(b * NL + l) * NWIN + d0 + c4);
      tile[r][c4 + 0] = v.x; tile[r][c4 + 1] = v.y;
      tile[r][c4 + 2] = v.z; tile[r][c4 + 3] = v.w;
    }
    __syncthreads();
    float outv[16];
#pragma unroll
    for (int k2 = 0; k2 < 16; ++k2) {
      int dj = dj0 + k2 * 4;
      int d = d0 + dj;
      float acc = cb[d];
#pragma unroll
      for (int k = 0; k < 4; ++k) acc += cw[k * NDIN + d] * tile[li + k][dj];
      acc = acc / (1.f + __expf(-acc));
      outv[k2] = acc;
      xc_t[(size_t)d * NTOK + b * NL + l0 + li] = acc;
    }
    __syncthreads();
#pragma unroll
    for (int k2 = 0; k2 < 16; ++k2) tile[li][dj0 + k2 * 4] = outv[k2];
    __syncthreads();
    for (int u = tid; u < 1024; u += 256) {
      int r = u >> 4, c4 = (u & 15) * 4;
      unsigned long long pk =
          (unsigned long long)f2bf(tile[r][c4 + 0]) |
          ((unsigned long long)f2bf(tile[r][c4 + 1]) << 16) |
          ((unsigned long long)f2bf(tile[r][c4 + 2]) << 32) |
          ((unsigned long long)f2bf(tile[r][c4 + 3]) << 48);
      *(unsigned long long*)(xcb + (size_t)(b * NL + l0 + r) * NDIN + d0 + c4) = pk;
    }
  } else {
    for (int u = tid; u < 64 * 16; u += 256) {
      int r = u >> 4, c4 = (u & 15) * 4;
      float4 v = *reinterpret_cast<const float4*>(xr + (size_t)(b * NL + l0 + r) * NWIN + NDIN + d0 + c4);
      tile[r][c4 + 0] = v.x; tile[r][c4 + 1] = v.y;
      tile[r][c4 + 2] = v.z; tile[r][c4 + 3] = v.w;
    }
    __syncthreads();
    for (int dj = dj0; dj < 64; dj += 4)
      res_t[(size_t)(d0 + dj) * NTOK + b * NL + l0 + li] = tile[li][dj];
  }
}

// selective scan: packed dword operands (dt pairs, B/C pairs), exp2-folded A.
__global__ __launch_bounds__(256) void scan9_kernel(
    const float* __restrict__ xc_t, const unsigned int* __restrict__ xdp,
    const float* __restrict__ w_dt, const float* __restrict__ b_dt,
    const float* __restrict__ A_log, const float* __restrict__ Dp,
    const float* __restrict__ res_t, float* __restrict__ yf_t) {
  __shared__ float yl[4][NL];
  __shared__ float u_lds[NL];
  int b = blockIdx.x >> 9, d = blockIdx.x & 511;
  int tid = threadIdx.x, lane = tid & 63, wv = tid >> 6;
  int bbase = b * NL;
  const float* urow = xc_t + (size_t)d * NTOK;

  for (int e = tid; e < NL; e += 256) u_lds[e] = urow[bbase + e];

  float wdt[16];
#pragma unroll
  for (int r = 0; r < 16; ++r) wdt[r] = w_dt[r * NDIN + d];
  float dl[9];
#pragma unroll
  for (int j = 0; j < 9; ++j) dl[j] = b_dt[d];
#pragma unroll
  for (int pr = 0; pr < 8; ++pr) {
    const unsigned int* p = xdp + (size_t)pr * NTOK + bbase;
    float w0 = wdt[2 * pr], w1 = wdt[2 * pr + 1];
#pragma unroll
    for (int j = 0; j < 9; ++j) {
      unsigned int u = p[j * 64 + lane];
      dl[j] += b2f((unsigned short)u) * w0 + b2f((unsigned short)(u >> 16)) * w1;
    }
  }
#pragma unroll
  for (int j = 0; j < 9; ++j) {
    float v = dl[j];
    dl[j] = fmaxf(v, 0.f) + __logf(1.f + __expf(-fabsf(v)));
  }
  __syncthreads();

  float ul[9];
#pragma unroll
  for (int j = 0; j < 9; ++j) ul[j] = u_lds[lane * 9 + j];
  float pre[9];
  float s = 0.f;
#pragma unroll
  for (int j = 0; j < 9; ++j) { s += dl[j]; pre[j] = s; }
  float isc = wave_iscan(s, lane);
  float total = __int_as_float(__builtin_amdgcn_readlane(__float_as_int(isc), 63));
  float excl = isc - s;
  float Ts[9], dlul[9];
#pragma unroll
  for (int j = 0; j < 9; ++j) {
    Ts[j] = total - excl - pre[j];
    dlul[j] = dl[j] * ul[j];
  }

  const float* Arow = A_log + (size_t)d * NDST + wv * 12;
  const unsigned int* bcP = xdp + (size_t)8 * NTOK;
  float y[9] = {};
  for (int jj = 0; jj < 12; ++jj) {
    float An2 = -__expf(Arow[jj]) * 1.44269504088896f;   // fold 1/ln2 -> exp2
    const unsigned int* p = bcP + (size_t)(wv * 12 + jj) * NTOK + bbase;
    unsigned int bc[9];
    float e[9], w[9];
    float ps = 0.f;
#pragma unroll
    for (int j = 0; j < 9; ++j) {
      bc[j] = p[j * 64 + lane];
      e[j] = exp2f(An2 * Ts[j]);
      ps += dlul[j] * b2f((unsigned short)bc[j]) * e[j];
      w[j] = ps;
    }
    float wi = wave_iscan(ps, lane);
    float wexcl = wi - ps;
#pragma unroll
    for (int j = 0; j < 9; ++j)
      y[j] += __fdividef(w[j] + wexcl, e[j] + 1e-12f) * b2f((unsigned short)(bc[j] >> 16));
  }
#pragma unroll
  for (int j = 0; j < 9; ++j) yl[wv][lane * 9 + j] = y[j];
  __syncthreads();

  const float* rrow = res_t + (size_t)d * NTOK;
  float* orow = yf_t + (size_t)d * NTOK;
  float Dd = Dp[d];
  for (int e0 = tid; e0 < NL; e0 += 256) {
    float yy = yl[0][e0] + yl[1][e0] + yl[2][e0] + yl[3][e0];
    float uu = u_lds[e0];
    float rr = rrow[bbase + e0];
    float yv = yy + uu * Dd;
    float sr = rr / (1.f + __expf(-rr));
    orow[bbase + e0] = yv * sr;
  }
}

// forward rfft on matrix cores: RF = Cf@f, IF = Sf@f.
__global__ __launch_bounds__(256) void dftf_mfma_kernel(
    const unsigned short* __restrict__ Cf, const unsigned short* __restrict__ Sf,
    const unsigned short* __restrict__ ft,
    unsigned short* __restrict__ RFb, unsigned short* __restrict__ IFb) {
  __shared__ unsigned short AsC[64][40], AsS[64][40], Bs[64][40];
  int tid = threadIdx.x;
  int lane = tid & 63, wv = tid >> 6;
  int n0 = blockIdx.x * 64, m0 = blockIdx.y * 64, b = blockIdx.z;
  int sm = tid >> 2, part = tid & 3;
  f32x4 accR[4] = {}, accI[4] = {};
  for (int k0 = 0; k0 < NL; k0 += 32) {
    *(bf16x8*)&AsC[sm][part * 8] = *(const bf16x8*)(Cf + (size_t)(m0 + sm) * NL + k0 + part * 8);
    *(bf16x8*)&AsS[sm][part * 8] = *(const bf16x8*)(Sf + (size_t)(m0 + sm) * NL + k0 + part * 8);
    *(bf16x8*)&Bs[sm][part * 8]  = *(const bf16x8*)(ft + (size_t)(n0 + sm) * NTOK + b * NL + k0 + part * 8);
    __syncthreads();
    int am = wv * 16 + (lane & 15);
    int koff = (lane >> 4) * 8;
    bf16x8 ac = *(bf16x8*)&AsC[am][koff];
    bf16x8 as = *(bf16x8*)&AsS[am][koff];
#pragma unroll
    for (int t = 0; t < 4; ++t) {
      bf16x8 bv = *(bf16x8*)&Bs[t * 16 + (lane & 15)][koff];
      accR[t] = __builtin_amdgcn_mfma_f32_16x16x32_bf16(ac, bv, accR[t], 0, 0, 0);
      accI[t] = __builtin_amdgcn_mfma_f32_16x16x32_bf16(as, bv, accI[t], 0, 0, 0);
    }
    __syncthreads();
  }
#pragma unroll
  for (int t = 0; t < 4; ++t) {
    int gn = n0 + t * 16 + (lane & 15);
#pragma unroll
    for (int r = 0; r < 4; ++r) {
      int gm = m0 + wv * 16 + (lane >> 4) * 4 + r;
      if (gm < NFREQ) {
        size_t o = ((size_t)(b * NFREQ + gm)) * NDIN + gn;
        RFb[o] = f2bf(accR[t][r]);
        IFb[o] = f2bf(accI[t][r]);
      }
    }
  }
}

// complex mix -> packed irfft B-matrix PK (bf16).
__global__ __launch_bounds__(256) void mix_mfma_kernel(
    const unsigned short* __restrict__ RFb, const unsigned short* __restrict__ IFb,
    const unsigned short* __restrict__ Wrt, const unsigned short* __restrict__ Wit,
    const float* __restrict__ rb, const float* __restrict__ ib,
    unsigned short* __restrict__ PK) {
  __shared__ unsigned short AsR[64][40], AsI[64][40], BsR[64][40], BsI[64][40];
  int tid = threadIdx.x;
  int lane = tid & 63, wv = tid >> 6;
  int n0 = blockIdx.x * 64, m0 = blockIdx.y * 64;
  int sm = tid >> 2, part = tid & 3;
  f32x4 accR[4] = {}, accI[4] = {};
  for (int k0 = 0; k0 < NDIN; k0 += 32) {
    *(bf16x8*)&AsR[sm][part * 8] = *(const bf16x8*)(Wrt + (size_t)(m0 + sm) * NDIN + k0 + part * 8);
    *(bf16x8*)&AsI[sm][part * 8] = *(const bf16x8*)(Wit + (size_t)(m0 + sm) * NDIN + k0 + part * 8);
    bf16x8 brf = {}, bif = {};
    if (n0 + sm < NMROW) {
      brf = *(const bf16x8*)(RFb + (size_t)(n0 + sm) * NDIN + k0 + part * 8);
      bif = *(const bf16x8*)(IFb + (size_t)(n0 + sm) * NDIN + k0 + part * 8);
    }
    *(bf16x8*)&BsR[sm][part * 8] = brf;
    *(bf16x8*)&BsI[sm][part * 8] = bif;
    __syncthreads();
    int am = wv * 16 + (lane & 15);
    int koff = (lane >> 4) * 8;
    bf16x8 a_wr = *(bf16x8*)&AsR[am][koff];
    bf16x8 a_wi = *(bf16x8*)&AsI[am][koff];
    union { bf16x8 h; i32x4 i; } un;
    un.h = a_wi;
    un.i = un.i ^ (int)0x80008000;
    bf16x8 a_win = un.h;
#pragma unroll
    for (int t = 0; t < 4; ++t) {
      bf16x8 b_rf = *(bf16x8*)&BsR[t * 16 + (lane & 15)][koff];
      bf16x8 b_if = *(bf16x8*)&BsI[t * 16 + (lane & 15)][koff];
      accR[t] = __builtin_amdgcn_mfma_f32_16x16x32_bf16(a_wr, b_rf, accR[t], 0, 0, 0);
      accR[t] = __builtin_amdgcn_mfma_f32_16x16x32_bf16(a_win, b_if, accR[t], 0, 0, 0);
      accI[t] = __builtin_amdgcn_mfma_f32_16x16x32_bf16(a_wr, b_if, accI[t], 0, 0, 0);
      accI[t] = __builtin_amdgcn_mfma_f32_16x16x32_bf16(a_wi, b_rf, accI[t], 0, 0, 0);
    }
    __syncthreads();
  }
#pragma unroll
  for (int t = 0; t < 4; ++t) {
    int gn = n0 + t * 16 + (lane & 15);   // freq global
    int bb = (gn >= 3 * NFREQ) ? 3 : (gn >= 2 * NFREQ) ? 2 : (gn >= NFREQ) ? 1 : 0;
    int kf = gn - bb * NFREQ;
    bool ok = gn < NMROW;
#pragma unroll
    for (int r = 0; r < 4; ++r) {
      int gm = m0 + wv * 16 + (lane >> 4) * 4 + r;   // c_out
      if (ok) {
        float vr = fmaxf(accR[t][r] + rb[gm], 0.f);
        float vi = fmaxf(accI[t][r] + ib[gm], 0.f);
        size_t base = ((size_t)gm * NB + bb) * NKPK;
        PK[base + kf] = f2bf(vr);
        PK[base + NFREQ + kf] = f2bf(vi);
      }
    }
  }
}

// irfft on matrix cores -> ffb bf16 [2304][512]; pad lanes masked in-register.
__global__ __launch_bounds__(256) void idft_mfma_kernel(
    const unsigned short* __restrict__ Ci, const unsigned short* __restrict__ PK,
    unsigned short* __restrict__ ffb) {
  __shared__ unsigned short As[64][40], Bs[64][40];
  int tid = threadIdx.x;
  int lane = tid & 63, wv = tid >> 6;
  int n0 = blockIdx.x * 64, m0 = blockIdx.y * 64, b = blockIdx.z;
  int sm = tid >> 2, part = tid & 3;
  f32x4 acc[4] = {};
  for (int k0 = 0; k0 < NKPK; k0 += 32) {
    *(bf16x8*)&As[sm][part * 8] = *(const bf16x8*)(Ci + (size_t)(m0 + sm) * NKPK + k0 + part * 8);
    bf16x8 bv = *(const bf16x8*)(PK + ((size_t)(n0 + sm) * NB + b) * NKPK + k0 + part * 8);
    if (k0 + part * 8 >= 2 * NFREQ - 2) {
      union { bf16x8 h; i32x4 i; } u;
      u.h = bv;
      if (k0 + part * 8 == 576) { u.i[1] = 0; u.i[2] = 0; u.i[3] = 0; }
      else { u.i[0] = 0; u.i[1] = 0; u.i[2] = 0; u.i[3] = 0; }
      bv = u.h;
    }
    *(bf16x8*)&Bs[sm][part * 8] = bv;
    __syncthreads();
    int am = wv * 16 + (lane & 15);
    int koff = (lane >> 4) * 8;
    bf16x8 av = *(bf16x8*)&As[am][koff];
#pragma unroll
    for (int t = 0; t < 4; ++t) {
      bf16x8 b2 = *(bf16x8*)&Bs[t * 16 + (lane & 15)][koff];
      acc[t] = __builtin_amdgcn_mfma_f32_16x16x32_bf16(av, b2, acc[t], 0, 0, 0);
    }
    __syncthreads();
  }
#pragma unroll
  for (int t = 0; t < 4; ++t) {
    int gn = n0 + t * 16 + (lane & 15);     // d
#pragma unroll
    for (int r = 0; r < 4; ++r) {
      int gm = m0 + wv * 16 + (lane >> 4) * 4 + r;   // l
      ffb[((size_t)(b * NL + gm)) * NDIN + gn] = f2bf(acc[t][r]);
    }
  }
}

extern "C" void kernel_launch(void* const* d_in, const int* in_sizes, int n_in,
                              void* d_out, int out_size, void* d_ws, size_t ws_size,
                              hipStream_t stream) {
  const float* x      = (const float*)d_in[0];
  const float* ln1_g  = (const float*)d_in[1];
  const float* ln1_b  = (const float*)d_in[2];
  const float* mln_g  = (const float*)d_in[3];
  const float* mln_b  = (const float*)d_in[4];
  const float* w_in   = (const float*)d_in[5];
  const float* conv_w = (const float*)d_in[6];
  const float* conv_b = (const float*)d_in[7];
  const float* w_xprj = (const float*)d_in[8];
  const float* w_dt   = (const float*)d_in[9];
  const float* b_dt   = (const float*)d_in[10];
  const float* A_log  = (const float*)d_in[11];
  const float* Dp     = (const float*)d_in[12];
  const float* w_out  = (const float*)d_in[13];
  const float* ln2_g  = (const float*)d_in[14];
  const float* ln2_b  = (const float*)d_in[15];
  const float* fc1_w  = (const float*)d_in[16];
  const float* bn1_s  = (const float*)d_in[17];
  const float* bn1_b  = (const float*)d_in[18];
  const float* Wr     = (const float*)d_in[19];
  const float* Wi     = (const float*)d_in[20];
  const float* rb     = (const float*)d_in[21];
  const float* ib     = (const float*)d_in[22];
  const float* fc2_w  = (const float*)d_in[23];
  const float* bn2_s  = (const float*)d_in[24];
  const float* bn2_b  = (const float*)d_in[25];

  float* ws = (float*)d_ws;
  unsigned short* hb   = (unsigned short*)(ws + OFF_HB);   // reused as h2b
  float* xr     = ws + OFF_XRF;
  float* xc_t   = ws + OFF_XCT;
  float* res_t  = ws + OFF_REST;
  float* yf_t   = ws + OFF_YFT;
  float* x2     = ws + OFF_X2;
  unsigned short* xcb  = (unsigned short*)(ws + OFF_XCB);
  unsigned int*   xdp  = (unsigned int*)(ws + OFF_XDBL);   // packed dt/BC
  unsigned short* PK   = (unsigned short*)(ws + OFF_YFT);
  unsigned short* ftb  = (unsigned short*)(ws + OFF_FTB);
  unsigned short* RFb  = (unsigned short*)(ws + OFF_RF);
  unsigned short* IFb  = (unsigned short*)(ws + OFF_IF);
  unsigned short* yfb  = (unsigned short*)(ws + OFF_YFB);
  unsigned short* ffb  = (unsigned short*)(ws + OFF_FFB);
  unsigned short* winT = (unsigned short*)(ws + OFF_WINT);
  unsigned short* Wrt  = (unsigned short*)(ws + OFF_WRT);
  unsigned short* Wit  = (unsigned short*)(ws + OFF_WIT);
  unsigned short* wxpT = (unsigned short*)(ws + OFF_WXPT);
  unsigned short* woT  = (unsigned short*)(ws + OFF_WOT);
  unsigned short* fc1T = (unsigned short*)(ws + OFF_FC1T);
  unsigned short* fc2T = (unsigned short*)(ws + OFF_FC2T);
  unsigned short* Cfb  = (unsigned short*)(ws + OFF_CF);
  unsigned short* Sfb  = (unsigned short*)(ws + OFF_SF);
  unsigned short* Cib  = (unsigned short*)(ws + OFF_CI);
  unsigned short* h2b  = hb;
  float* out = (float*)d_out;

  // 1: all weight packs + trig matrices + first double-LN in one launch
  setup_kernel<<<1032, 256, 0, stream>>>(w_in, Wr, Wi, w_xprj, w_out, fc1_w, fc2_w,
                                         winT, Wrt, Wit, wxpT, woT, fc1T, fc2T,
                                         Cfb, Sfb, Cib,
                                         x, hb, ln1_g, ln1_b, mln_g, mln_b);
  // 2: xr = hb @ w_in (f32)
  gemm_mfma<<<dim3(16, 36), 256, 0, stream>>>(hb, winT, xr, NWIN, NTOK, NWIN, NC,
                                              0, 0, nullptr, nullptr, nullptr, 0);
  // 3: xc_t f32 + xcb bf16 + res_t
  convT_kernel<<<dim3(8, 36, 2), 256, 0, stream>>>(xr, conv_w, conv_b, xc_t, res_t, xcb);
  // 4: packed xdbl = (xcb @ w_xproj)^T (dt pairs + B/C pairs, token-permuted)
  gemm_mfma<<<dim3(2, 36), 256, 0, stream>>>(xcb, wxpT, xdp, NTOK, NTOK, NXD, NDIN,
                                             0, 16, nullptr, nullptr, nullptr, 0);
  // 5: scan (fused delta, packed dword loads, exp2)
  scan9_kernel<<<NB * NDIN, 256, 0, stream>>>(xc_t, xdp, w_dt, b_dt, A_log, Dp, res_t, yf_t);
  // 6: yfb = bf16(yf^T)
  packT_kernel<<<dim3(36, 8), 256, 0, stream>>>(yf_t, yfb, NDIN, NTOK);
  // 7: x2 = x + yfb @ w_out
  gemm_mfma<<<dim3(4, 36), 256, 0, stream>>>(yfb, woT, x2, NC, NTOK, NC, NDIN,
                                             2, 0, nullptr, nullptr, x, NC);
  // 8: h2b = bf16(LN(x2))
  ln_kernel<<<NTOK, 64, 0, stream>>>(x2, h2b, ln2_g, ln2_b);
  // 9: ftb = bf16(relu(h2b@fc1 * s + b))^T [512][2304]
  gemm_mfma<<<dim3(8, 36), 256, 0, stream>>>(h2b, fc1T, ftb, NTOK, NTOK, NDIN, NC,
                                             3, 6, bn1_s, bn1_b, nullptr, 0);
  // 10-12: rfft / mix / irfft on MFMA (idft masks PK pad lanes in-register)
  dftf_mfma_kernel<<<dim3(8, 5, NB), 256, 0, stream>>>(Cfb, Sfb, ftb, RFb, IFb);
  mix_mfma_kernel<<<dim3(19, 8), 256, 0, stream>>>(RFb, IFb, Wrt, Wit, rb, ib, PK);
  idft_mfma_kernel<<<dim3(8, 9, NB), 256, 0, stream>>>(Cib, PK, ffb);
  // 13: out = x2 + ffb @ fc2 * s + b
  gemm_mfma<<<dim3(4, 36), 256, 0, stream>>>(ffb, fc2T, out, NC, NTOK, NC, NDIN,
                                             4, 0, bn2_s, bn2_b, x2, NC);
}

// Round 15
// 181.111 us; speedup vs baseline: 1.0354x; 1.0354x over previous
//
#include <hip/hip_runtime.h>
#include <math.h>

#define NB 4
#define NL 576
#define NC 256
#define NTOK (NB*NL)      // 2304
#define NDIN 512
#define NXD 112
#define NDTR 16
#define NDST 48
#define NFREQ 289
#define NWIN 1024
#define NMROW (NB*NFREQ)  // 1156
#define NKPK 608          // packed K for irfft (2*289 -> 608)

// ---- workspace layout (f32-equivalent offsets) ----
#define OFF_HB    0u          // hb bf16 [2304][256] (reused as h2b)
#define OFF_XRF   147456u     // xr f32 [2304][1024]
#define OFF_XCT   2506752u    // xc_t f32 [512][2304]
#define OFF_REST  3686400u    // res_t f32 [512][2304]
#define OFF_XCB   4866048u    // xcb bf16 [2304][512]
#define OFF_XDBL  5455872u    // xdbl bf16 [112][2304] (token-permuted)
#define OFF_YFT   5584896u    // yf_t f32 [512][2304] -> PK bf16 [2048][608] later
#define OFF_X2    6764544u    // x2 f32 [2304][256]
#define OFF_FTB   7354368u    // ftb bf16 [512][2304]
#define OFF_RF    7944192u    // RFb bf16 [1156][512]
#define OFF_IF    8240128u    // IFb bf16
#define OFF_FFB   9125888u    // ffb bf16 [2304][512]
#define OFF_WINT  9715712u    // winT bf16 [1024][256]
#define OFF_WRT   9846784u    // Wrt bf16 [512][512]
#define OFF_WIT   9977856u    // Wit bf16 [512][512]
#define OFF_WXPT  10108928u   // wxpT bf16 [112][512]
#define OFF_WOT   10137600u   // woT bf16 [256][512]
#define OFF_FC1T  10203136u   // fc1T bf16 [512][256]
#define OFF_FC2T  10268672u   // fc2T bf16 [256][512]
#define OFF_CF    10334208u   // Cfb bf16 [320][576]
#define OFF_SF    10426368u   // Sfb bf16 [320][576]
#define OFF_CI    10518528u   // Cib bf16 [576][608]   end 10693632

typedef __attribute__((ext_vector_type(8))) short bf16x8;
typedef __attribute__((ext_vector_type(4))) float f32x4;
typedef __attribute__((ext_vector_type(4))) int   i32x4;

__device__ __forceinline__ float wave_sum(float v) {
#pragma unroll
  for (int o = 32; o > 0; o >>= 1) v += __shfl_xor(v, o);
  return v;
}

__device__ __forceinline__ unsigned short f2bf(float f) {
  unsigned int u = __float_as_uint(f);
  unsigned int r = (u + 0x7fffu + ((u >> 16) & 1u)) >> 16;  // RNE
  return (unsigned short)r;
}
__device__ __forceinline__ float b2f(unsigned short u) {
  return __uint_as_float(((unsigned int)u) << 16);
}

// 64-lane inclusive prefix sum via DPP + readlane broadcasts.
__device__ __forceinline__ float wave_iscan(float x, int lane) {
  x += __int_as_float(__builtin_amdgcn_update_dpp(0, __float_as_int(x), 0x111, 0xf, 0xf, true));
  x += __int_as_float(__builtin_amdgcn_update_dpp(0, __float_as_int(x), 0x112, 0xf, 0xf, true));
  x += __int_as_float(__builtin_amdgcn_update_dpp(0, __float_as_int(x), 0x114, 0xf, 0xf, true));
  x += __int_as_float(__builtin_amdgcn_update_dpp(0, __float_as_int(x), 0x118, 0xf, 0xf, true));
  int xi = __float_as_int(x);
  float s15 = __int_as_float(__builtin_amdgcn_readlane(xi, 15));
  float s31 = __int_as_float(__builtin_amdgcn_readlane(xi, 31));
  float s47 = __int_as_float(__builtin_amdgcn_readlane(xi, 47));
  float off = 0.f;
  if (lane >= 16) off += s15;
  if (lane >= 32) off += s31;
  if (lane >= 48) off += s47;
  return x + off;
}

// device-side 64x64 transpose+bf16 pack tile
__device__ void packT_dev(const float* __restrict__ src, unsigned short* __restrict__ dst,
                          int R, int C, int tile, int cblks) {
  __shared__ float t[64][65];
  int cb = tile % cblks, rb = tile / cblks;
  int c0 = cb * 64, r0 = rb * 64;
  int tid = threadIdx.x;
  for (int u = tid; u < 4096; u += 256) {
    int r = u >> 6, c = u & 63;
    float v = 0.f;
    if (r0 + r < R && c0 + c < C) v = src[(size_t)(r0 + r) * C + c0 + c];
    t[r][c] = v;
  }
  __syncthreads();
  for (int u = tid; u < 4096; u += 256) {
    int nr = u >> 6, nc = u & 63;
    if (c0 + nr < C && r0 + nc < R)
      dst[(size_t)(c0 + nr) * R + r0 + nc] = f2bf(t[nc][nr]);
  }
}

// double LayerNorm over one row (wave-level), bf16 out.
__device__ void ln_row2(const float* __restrict__ in, unsigned short* __restrict__ out,
                        const float* __restrict__ g1, const float* __restrict__ b1,
                        const float* __restrict__ g2, const float* __restrict__ b2,
                        int row, int lane) {
  const float* p = in + (size_t)row * NC;
  float v[4];
#pragma unroll
  for (int j = 0; j < 4; ++j) v[j] = p[lane + j * 64];
  float s = wave_sum(v[0] + v[1] + v[2] + v[3]);
  float m = s * (1.f / NC);
  float q = 0.f;
#pragma unroll
  for (int j = 0; j < 4; ++j) { float dd = v[j] - m; q += dd * dd; }
  q = wave_sum(q);
  float rs = 1.f / sqrtf(q * (1.f / NC) + 1e-3f);
#pragma unroll
  for (int j = 0; j < 4; ++j) {
    int c = lane + j * 64;
    v[j] = (v[j] - m) * rs * g1[c] + b1[c];
  }
  s = wave_sum(v[0] + v[1] + v[2] + v[3]);
  m = s * (1.f / NC);
  q = 0.f;
#pragma unroll
  for (int j = 0; j < 4; ++j) { float dd = v[j] - m; q += dd * dd; }
  q = wave_sum(q);
  rs = 1.f / sqrtf(q * (1.f / NC) + 1e-3f);
  unsigned short* o = out + (size_t)row * NC;
#pragma unroll
  for (int j = 0; j < 4; ++j) {
    int c = lane + j * 64;
    o[c] = f2bf((v[j] - m) * rs * g2[c] + b2[c]);
  }
}

// ONE setup kernel: all weight packs + trig matrices + first double-LN.
__global__ __launch_bounds__(256) void setup_kernel(
    const float* __restrict__ w_in, const float* __restrict__ Wr,
    const float* __restrict__ Wi, const float* __restrict__ wxp,
    const float* __restrict__ wo, const float* __restrict__ fc1,
    const float* __restrict__ fc2,
    unsigned short* __restrict__ winT, unsigned short* __restrict__ Wrt,
    unsigned short* __restrict__ Wit, unsigned short* __restrict__ wxpT,
    unsigned short* __restrict__ woT, unsigned short* __restrict__ fc1T,
    unsigned short* __restrict__ fc2T, unsigned short* __restrict__ Cf,
    unsigned short* __restrict__ Sf, unsigned short* __restrict__ Ci,
    const float* __restrict__ x, unsigned short* __restrict__ hb,
    const float* __restrict__ ln1_g, const float* __restrict__ ln1_b,
    const float* __restrict__ mln_g, const float* __restrict__ mln_b) {
  int bid = blockIdx.x;
  const float TWO_PI_N = 6.28318530717958647692f / (float)NL;
  if (bid < 64)       packT_dev(w_in, winT, NC, NWIN, bid, 16);
  else if (bid < 128) packT_dev(Wr, Wrt, NDIN, NDIN, bid - 64, 8);
  else if (bid < 192) packT_dev(Wi, Wit, NDIN, NDIN, bid - 128, 8);
  else if (bid < 208) packT_dev(wxp, wxpT, NDIN, NXD, bid - 192, 2);
  else if (bid < 240) packT_dev(wo, woT, NDIN, NC, bid - 208, 4);
  else if (bid < 272) packT_dev(fc1, fc1T, NC, NDIN, bid - 240, 8);
  else if (bid < 304) packT_dev(fc2, fc2T, NDIN, NC, bid - 272, 4);
  else if (bid < 384) {            // Cf/Sf: 80 blocks x 4 m-rows
    int m0 = (bid - 304) * 4;
    for (int u = threadIdx.x; u < 4 * NL; u += 256) {
      int m = m0 + u / NL, l = u % NL;
      float c = 0.f, s = 0.f;
      if (m < NFREQ) {
        int idx = (m * l) % NL;
        float sv, cv;
        __sincosf(TWO_PI_N * idx, &sv, &cv);
        c = cv * (1.f / 24.f);
        s = -sv * (1.f / 24.f);
      }
      Cf[(size_t)m * NL + l] = f2bf(c);
      Sf[(size_t)m * NL + l] = f2bf(s);
    }
  } else if (bid < 456) {          // Ci: 72 blocks x 8 l-rows
    int l0 = (bid - 384) * 8;
    for (int u = threadIdx.x; u < 8 * NKPK; u += 256) {
      int l = l0 + u / NKPK, k = u % NKPK;
      float v = 0.f;
      if (k < NFREQ) {
        float w = (k == 0 || k == NFREQ - 1) ? 1.f : 2.f;
        int idx = (k * l) % NL;
        float sv, cv;
        __sincosf(TWO_PI_N * idx, &sv, &cv);
        v = w * cv * (1.f / 24.f);
      } else if (k < 2 * NFREQ) {
        int kk = k - NFREQ;
        float w = (kk == 0 || kk == NFREQ - 1) ? 1.f : 2.f;
        int idx = (kk * l) % NL;
        float sv, cv;
        __sincosf(TWO_PI_N * idx, &sv, &cv);
        v = -w * sv * (1.f / 24.f);
      }
      Ci[(size_t)l * NKPK + k] = f2bf(v);
    }
  } else {                         // ln1: 576 blocks x 4 rows (wave per row)
    int row = (bid - 456) * 4 + (threadIdx.x >> 6);
    ln_row2(x, hb, ln1_g, ln1_b, mln_g, mln_b, row, threadIdx.x & 63);
  }
}

// one wave per token row; bf16 output (single LN).
__global__ void ln_kernel(const float* __restrict__ in, unsigned short* __restrict__ out,
                          const float* __restrict__ g1, const float* __restrict__ b1) {
  int row = blockIdx.x, lane = threadIdx.x;
  const float* p = in + (size_t)row * NC;
  float v[4];
#pragma unroll
  for (int j = 0; j < 4; ++j) v[j] = p[lane + j * 64];
  float s = wave_sum(v[0] + v[1] + v[2] + v[3]);
  float m = s * (1.f / NC);
  float q = 0.f;
#pragma unroll
  for (int j = 0; j < 4; ++j) { float d = v[j] - m; q += d * d; }
  q = wave_sum(q);
  float rs = 1.f / sqrtf(q * (1.f / NC) + 1e-3f);
  unsigned short* o = out + (size_t)row * NC;
#pragma unroll
  for (int j = 0; j < 4; ++j) {
    int c = lane + j * 64;
    o[c] = f2bf((v[j] - m) * rs * g1[c] + b1[c]);
  }
}

// generic MFMA GEMM: C = A[M][K]bf16 @ B[N][K]bf16^T (f32 accum), fused epilogues.
// mode 0: store; 2: v+add; 3: relu(v*scl+bias); 4: v*scl+bias+add
// flags bit1: transposed store C[n][m]; bit2: bf16 store;
// flags bit3: scan-permute token index on transposed store;
// flags bit5: A is f32 K-major [K][NTOK] (yf_t) -> stage+convert in LDS.
__global__ __launch_bounds__(256) void gemm_mfma(
    const unsigned short* __restrict__ A, const unsigned short* __restrict__ B,
    void* __restrict__ C, int ldc, int M, int N, int K, int mode, int flags,
    const float* __restrict__ scl, const float* __restrict__ bias,
    const float* __restrict__ add, int ldadd) {
  __shared__ unsigned short As[64][40], Bs[64][40];
  int tid = threadIdx.x, lane = tid & 63, wv = tid >> 6;
  int n0 = blockIdx.x * 64, m0 = blockIdx.y * 64;
  int sm = tid >> 2, part = tid & 3;
  f32x4 acc[4] = {};
  for (int k0 = 0; k0 < K; k0 += 32) {
    if (flags & 32) {
      const float* Af = (const float*)A;   // [K][NTOK] f32
      int kr = tid >> 4;                    // 0..15
      int mq = (tid & 15) * 4;              // 0..60
#pragma unroll
      for (int it = 0; it < 2; ++it) {
        int kk = kr + it * 16;
        float4 v = *(const float4*)(Af + (size_t)(k0 + kk) * NTOK + m0 + mq);
        As[mq + 0][kk] = f2bf(v.x);
        As[mq + 1][kk] = f2bf(v.y);
        As[mq + 2][kk] = f2bf(v.z);
        As[mq + 3][kk] = f2bf(v.w);
      }
    } else {
      *(bf16x8*)&As[sm][part * 8] = *(const bf16x8*)(A + (size_t)(m0 + sm) * K + k0 + part * 8);
    }
    bf16x8 bv = {};
    if (n0 + sm < N) bv = *(const bf16x8*)(B + (size_t)(n0 + sm) * K + k0 + part * 8);
    *(bf16x8*)&Bs[sm][part * 8] = bv;
    __syncthreads();
    int am = wv * 16 + (lane & 15), koff = (lane >> 4) * 8;
    bf16x8 a = *(bf16x8*)&As[am][koff];
#pragma unroll
    for (int t = 0; t < 4; ++t) {
      bf16x8 b = *(bf16x8*)&Bs[t * 16 + (lane & 15)][koff];
      acc[t] = __builtin_amdgcn_mfma_f32_16x16x32_bf16(a, b, acc[t], 0, 0, 0);
    }
    __syncthreads();
  }
#pragma unroll
  for (int t = 0; t < 4; ++t) {
    int gn = n0 + t * 16 + (lane & 15);
    if (gn >= N) continue;
    float sv = scl ? scl[gn] : 0.f, bvv = bias ? bias[gn] : 0.f;
#pragma unroll
    for (int r = 0; r < 4; ++r) {
      int gm = m0 + wv * 16 + (lane >> 4) * 4 + r;
      float v = acc[t][r];
      if (mode == 2) v += add[(size_t)gm * ldadd + gn];
      else if (mode == 3) v = fmaxf(v * sv + bvv, 0.f);
      else if (mode == 4) v = v * sv + bvv + add[(size_t)gm * ldadd + gn];
      int gms = gm;
      if (flags & 8) {
        int bq = gm / NL, tt = gm - bq * NL;
        int t9 = tt / 9;
        gms = bq * NL + (tt - t9 * 9) * 64 + t9;
      }
      size_t o = (flags & 2) ? (size_t)gn * ldc + gms : (size_t)gm * ldc + gn;
      if (flags & 4) ((unsigned short*)C)[o] = f2bf(v);
      else ((float*)C)[o] = v;
    }
  }
}

// Fused causal depthwise conv(4)+silu: xc_t f32 (d-major) + xcb bf16 (tok-major);
// z=1: res transpose -> res_t.
__global__ __launch_bounds__(256) void convT_kernel(
    const float* __restrict__ xr, const float* __restrict__ cw,
    const float* __restrict__ cb, float* __restrict__ xc_t,
    float* __restrict__ res_t, unsigned short* __restrict__ xcb) {
  __shared__ float tile[67][65];
  int d0 = blockIdx.x * 64;
  int rt = blockIdx.y;
  int b = rt / 9, l0 = (rt % 9) * 64;
  int tid = threadIdx.x;
  int li = tid & 63, dj0 = tid >> 6;
  if (blockIdx.z == 0) {
    for (int u = tid; u < 67 * 16; u += 256) {
      int r = u >> 4, c4 = (u & 15) * 4;
      int l = l0 - 3 + r;
      float4 v = make_float4(0.f, 0.f, 0.f, 0.f);
      if (l >= 0) v = *reinterpret_cast<const float4*>(xr + (size_t)(b * NL + l) * NWIN + d0 + c4);
      tile[r][c4 + 0] = v.x; tile[r][c4 + 1] = v.y;
      tile[r][c4 + 2] = v.z; tile[r][c4 + 3] = v.w;
    }
    __syncthreads();
    float outv[16];
#pragma unroll
    for (int k2 = 0; k2 < 16; ++k2) {
      int dj = dj0 + k2 * 4;
      int d = d0 + dj;
      float acc = cb[d];
#pragma unroll
      for (int k = 0; k < 4; ++k) acc += cw[k * NDIN + d] * tile[li + k][dj];
      acc = acc / (1.f + __expf(-acc));
      outv[k2] = acc;
      xc_t[(size_t)d * NTOK + b * NL + l0 + li] = acc;
    }
    __syncthreads();
#pragma unroll
    for (int k2 = 0; k2 < 16; ++k2) tile[li][dj0 + k2 * 4] = outv[k2];
    __syncthreads();
    for (int u = tid; u < 1024; u += 256) {
      int r = u >> 4, c4 = (u & 15) * 4;
      unsigned long long pk =
          (unsigned long long)f2bf(tile[r][c4 + 0]) |
          ((unsigned long long)f2bf(tile[r][c4 + 1]) << 16) |
          ((unsigned long long)f2bf(tile[r][c4 + 2]) << 32) |
          ((unsigned long long)f2bf(tile[r][c4 + 3]) << 48);
      *(unsigned long long*)(xcb + (size_t)(b * NL + l0 + r) * NDIN + d0 + c4) = pk;
    }
  } else {
    for (int u = tid; u < 64 * 16; u += 256) {
      int r = u >> 4, c4 = (u & 15) * 4;
      float4 v = *reinterpret_cast<const float4*>(xr + (size_t)(b * NL + l0 + r) * NWIN + NDIN + d0 + c4);
      tile[r][c4 + 0] = v.x; tile[r][c4 + 1] = v.y;
      tile[r][c4 + 2] = v.z; tile[r][c4 + 3] = v.w;
    }
    __syncthreads();
    for (int dj = dj0; dj < 64; dj += 4)
      res_t[(size_t)(d0 + dj) * NTOK + b * NL + l0 + li] = tile[li][dj];
  }
}

// selective scan with fused delta; xdbl bf16, token-permuted for coalescing.
__global__ __launch_bounds__(256) void scan7_kernel(
    const float* __restrict__ xc_t, const unsigned short* __restrict__ xdbl,
    const float* __restrict__ w_dt, const float* __restrict__ b_dt,
    const float* __restrict__ A_log, const float* __restrict__ Dp,
    const float* __restrict__ res_t, float* __restrict__ yf_t) {
  __shared__ float yl[4][NL];
  __shared__ float u_lds[NL];
  int b = blockIdx.x >> 9, d = blockIdx.x & 511;
  int tid = threadIdx.x, lane = tid & 63, wv = tid >> 6;
  int bbase = b * NL;
  const float* urow = xc_t + (size_t)d * NTOK;

  for (int e = tid; e < NL; e += 256) u_lds[e] = urow[bbase + e];

  float wdt[16];
#pragma unroll
  for (int r = 0; r < 16; ++r) wdt[r] = w_dt[r * NDIN + d];
  float bd = b_dt[d];
  float dl[9];
#pragma unroll
  for (int j = 0; j < 9; ++j) dl[j] = bd;
#pragma unroll
  for (int r = 0; r < 16; ++r) {
    const unsigned short* dtp = xdbl + (size_t)r * NTOK + bbase;
#pragma unroll
    for (int j = 0; j < 9; ++j) dl[j] += b2f(dtp[j * 64 + lane]) * wdt[r];
  }
#pragma unroll
  for (int j = 0; j < 9; ++j) {
    float v = dl[j];
    dl[j] = fmaxf(v, 0.f) + __logf(1.f + __expf(-fabsf(v)));
  }
  __syncthreads();

  float ul[9];
#pragma unroll
  for (int j = 0; j < 9; ++j) ul[j] = u_lds[lane * 9 + j];
  float pre[9];
  float s = 0.f;
#pragma unroll
  for (int j = 0; j < 9; ++j) { s += dl[j]; pre[j] = s; }
  float isc = wave_iscan(s, lane);
  float total = __int_as_float(__builtin_amdgcn_readlane(__float_as_int(isc), 63));
  float excl = isc - s;
  float Ts[9], dlul[9];
#pragma unroll
  for (int j = 0; j < 9; ++j) {
    Ts[j] = total - excl - pre[j];
    dlul[j] = dl[j] * ul[j];
  }

  const float* Arow = A_log + (size_t)d * NDST + wv * 12;
  float y[9] = {};
  for (int jj = 0; jj < 12; ++jj) {
    float An = -__expf(Arow[jj]);
    const unsigned short* bbp = xdbl + (size_t)(NDTR + wv * 12 + jj) * NTOK + bbase;
    const unsigned short* ccp = xdbl + (size_t)(NDTR + NDST + wv * 12 + jj) * NTOK + bbase;
    float e[9], w[9];
    float ps = 0.f;
#pragma unroll
    for (int j = 0; j < 9; ++j) {
      e[j] = __expf(An * Ts[j]);
      ps += dlul[j] * b2f(bbp[j * 64 + lane]) * e[j];
      w[j] = ps;
    }
    float wi = wave_iscan(ps, lane);
    float wexcl = wi - ps;
#pragma unroll
    for (int j = 0; j < 9; ++j)
      y[j] += __fdividef(w[j] + wexcl, e[j] + 1e-12f) * b2f(ccp[j * 64 + lane]);
  }
#pragma unroll
  for (int j = 0; j < 9; ++j) yl[wv][lane * 9 + j] = y[j];
  __syncthreads();

  const float* rrow = res_t + (size_t)d * NTOK;
  float* orow = yf_t + (size_t)d * NTOK;
  float Dd = Dp[d];
  for (int e0 = tid; e0 < NL; e0 += 256) {
    float yy = yl[0][e0] + yl[1][e0] + yl[2][e0] + yl[3][e0];
    float uu = u_lds[e0];
    float rr = rrow[bbase + e0];
    float yv = yy + uu * Dd;
    float sr = rr / (1.f + __expf(-rr));
    orow[bbase + e0] = yv * sr;
  }
}

// forward rfft on matrix cores: RF = Cf@f, IF = Sf@f.
__global__ __launch_bounds__(256) void dftf_mfma_kernel(
    const unsigned short* __restrict__ Cf, const unsigned short* __restrict__ Sf,
    const unsigned short* __restrict__ ft,
    unsigned short* __restrict__ RFb, unsigned short* __restrict__ IFb) {
  __shared__ unsigned short AsC[64][40], AsS[64][40], Bs[64][40];
  int tid = threadIdx.x;
  int lane = tid & 63, wv = tid >> 6;
  int n0 = blockIdx.x * 64, m0 = blockIdx.y * 64, b = blockIdx.z;
  int sm = tid >> 2, part = tid & 3;
  f32x4 accR[4] = {}, accI[4] = {};
  for (int k0 = 0; k0 < NL; k0 += 32) {
    *(bf16x8*)&AsC[sm][part * 8] = *(const bf16x8*)(Cf + (size_t)(m0 + sm) * NL + k0 + part * 8);
    *(bf16x8*)&AsS[sm][part * 8] = *(const bf16x8*)(Sf + (size_t)(m0 + sm) * NL + k0 + part * 8);
    *(bf16x8*)&Bs[sm][part * 8]  = *(const bf16x8*)(ft + (size_t)(n0 + sm) * NTOK + b * NL + k0 + part * 8);
    __syncthreads();
    int am = wv * 16 + (lane & 15);
    int koff = (lane >> 4) * 8;
    bf16x8 ac = *(bf16x8*)&AsC[am][koff];
    bf16x8 as = *(bf16x8*)&AsS[am][koff];
#pragma unroll
    for (int t = 0; t < 4; ++t) {
      bf16x8 bv = *(bf16x8*)&Bs[t * 16 + (lane & 15)][koff];
      accR[t] = __builtin_amdgcn_mfma_f32_16x16x32_bf16(ac, bv, accR[t], 0, 0, 0);
      accI[t] = __builtin_amdgcn_mfma_f32_16x16x32_bf16(as, bv, accI[t], 0, 0, 0);
    }
    __syncthreads();
  }
#pragma unroll
  for (int t = 0; t < 4; ++t) {
    int gn = n0 + t * 16 + (lane & 15);
#pragma unroll
    for (int r = 0; r < 4; ++r) {
      int gm = m0 + wv * 16 + (lane >> 4) * 4 + r;
      if (gm < NFREQ) {
        size_t o = ((size_t)(b * NFREQ + gm)) * NDIN + gn;
        RFb[o] = f2bf(accR[t][r]);
        IFb[o] = f2bf(accI[t][r]);
      }
    }
  }
}

// complex mix -> packed irfft B-matrix PK (bf16).
__global__ __launch_bounds__(256) void mix_mfma_kernel(
    const unsigned short* __restrict__ RFb, const unsigned short* __restrict__ IFb,
    const unsigned short* __restrict__ Wrt, const unsigned short* __restrict__ Wit,
    const float* __restrict__ rb, const float* __restrict__ ib,
    unsigned short* __restrict__ PK) {
  __shared__ unsigned short AsR[64][40], AsI[64][40], BsR[64][40], BsI[64][40];
  int tid = threadIdx.x;
  int lane = tid & 63, wv = tid >> 6;
  int n0 = blockIdx.x * 64, m0 = blockIdx.y * 64;
  int sm = tid >> 2, part = tid & 3;
  f32x4 accR[4] = {}, accI[4] = {};
  for (int k0 = 0; k0 < NDIN; k0 += 32) {
    *(bf16x8*)&AsR[sm][part * 8] = *(const bf16x8*)(Wrt + (size_t)(m0 + sm) * NDIN + k0 + part * 8);
    *(bf16x8*)&AsI[sm][part * 8] = *(const bf16x8*)(Wit + (size_t)(m0 + sm) * NDIN + k0 + part * 8);
    bf16x8 brf = {}, bif = {};
    if (n0 + sm < NMROW) {
      brf = *(const bf16x8*)(RFb + (size_t)(n0 + sm) * NDIN + k0 + part * 8);
      bif = *(const bf16x8*)(IFb + (size_t)(n0 + sm) * NDIN + k0 + part * 8);
    }
    *(bf16x8*)&BsR[sm][part * 8] = brf;
    *(bf16x8*)&BsI[sm][part * 8] = bif;
    __syncthreads();
    int am = wv * 16 + (lane & 15);
    int koff = (lane >> 4) * 8;
    bf16x8 a_wr = *(bf16x8*)&AsR[am][koff];
    bf16x8 a_wi = *(bf16x8*)&AsI[am][koff];
    union { bf16x8 h; i32x4 i; } un;
    un.h = a_wi;
    un.i = un.i ^ (int)0x80008000;
    bf16x8 a_win = un.h;
#pragma unroll
    for (int t = 0; t < 4; ++t) {
      bf16x8 b_rf = *(bf16x8*)&BsR[t * 16 + (lane & 15)][koff];
      bf16x8 b_if = *(bf16x8*)&BsI[t * 16 + (lane & 15)][koff];
      accR[t] = __builtin_amdgcn_mfma_f32_16x16x32_bf16(a_wr, b_rf, accR[t], 0, 0, 0);
      accR[t] = __builtin_amdgcn_mfma_f32_16x16x32_bf16(a_win, b_if, accR[t], 0, 0, 0);
      accI[t] = __builtin_amdgcn_mfma_f32_16x16x32_bf16(a_wr, b_if, accI[t], 0, 0, 0);
      accI[t] = __builtin_amdgcn_mfma_f32_16x16x32_bf16(a_wi, b_rf, accI[t], 0, 0, 0);
    }
    __syncthreads();
  }
#pragma unroll
  for (int t = 0; t < 4; ++t) {
    int gn = n0 + t * 16 + (lane & 15);   // freq global
    int bb = (gn >= 3 * NFREQ) ? 3 : (gn >= 2 * NFREQ) ? 2 : (gn >= NFREQ) ? 1 : 0;
    int kf = gn - bb * NFREQ;
    bool ok = gn < NMROW;
#pragma unroll
    for (int r = 0; r < 4; ++r) {
      int gm = m0 + wv * 16 + (lane >> 4) * 4 + r;   // c_out
      if (ok) {
        float vr = fmaxf(accR[t][r] + rb[gm], 0.f);
        float vi = fmaxf(accI[t][r] + ib[gm], 0.f);
        size_t base = ((size_t)gm * NB + bb) * NKPK;
        PK[base + kf] = f2bf(vr);
        PK[base + NFREQ + kf] = f2bf(vi);
      }
    }
  }
}

// irfft on matrix cores -> ffb bf16 [2304][512]; pad lanes masked in-register.
__global__ __launch_bounds__(256) void idft_mfma_kernel(
    const unsigned short* __restrict__ Ci, const unsigned short* __restrict__ PK,
    unsigned short* __restrict__ ffb) {
  __shared__ unsigned short As[64][40], Bs[64][40];
  int tid = threadIdx.x;
  int lane = tid & 63, wv = tid >> 6;
  int n0 = blockIdx.x * 64, m0 = blockIdx.y * 64, b = blockIdx.z;
  int sm = tid >> 2, part = tid & 3;
  f32x4 acc[4] = {};
  for (int k0 = 0; k0 < NKPK; k0 += 32) {
    *(bf16x8*)&As[sm][part * 8] = *(const bf16x8*)(Ci + (size_t)(m0 + sm) * NKPK + k0 + part * 8);
    bf16x8 bv = *(const bf16x8*)(PK + ((size_t)(n0 + sm) * NB + b) * NKPK + k0 + part * 8);
    if (k0 + part * 8 >= 2 * NFREQ - 2) {
      union { bf16x8 h; i32x4 i; } u;
      u.h = bv;
      if (k0 + part * 8 == 576) { u.i[1] = 0; u.i[2] = 0; u.i[3] = 0; }
      else { u.i[0] = 0; u.i[1] = 0; u.i[2] = 0; u.i[3] = 0; }
      bv = u.h;
    }
    *(bf16x8*)&Bs[sm][part * 8] = bv;
    __syncthreads();
    int am = wv * 16 + (lane & 15);
    int koff = (lane >> 4) * 8;
    bf16x8 av = *(bf16x8*)&As[am][koff];
#pragma unroll
    for (int t = 0; t < 4; ++t) {
      bf16x8 b2 = *(bf16x8*)&Bs[t * 16 + (lane & 15)][koff];
      acc[t] = __builtin_amdgcn_mfma_f32_16x16x32_bf16(av, b2, acc[t], 0, 0, 0);
    }
    __syncthreads();
  }
#pragma unroll
  for (int t = 0; t < 4; ++t) {
    int gn = n0 + t * 16 + (lane & 15);     // d
#pragma unroll
    for (int r = 0; r < 4; ++r) {
      int gm = m0 + wv * 16 + (lane >> 4) * 4 + r;   // l
      ffb[((size_t)(b * NL + gm)) * NDIN + gn] = f2bf(acc[t][r]);
    }
  }
}

extern "C" void kernel_launch(void* const* d_in, const int* in_sizes, int n_in,
                              void* d_out, int out_size, void* d_ws, size_t ws_size,
                              hipStream_t stream) {
  const float* x      = (const float*)d_in[0];
  const float* ln1_g  = (const float*)d_in[1];
  const float* ln1_b  = (const float*)d_in[2];
  const float* mln_g  = (const float*)d_in[3];
  const float* mln_b  = (const float*)d_in[4];
  const float* w_in   = (const float*)d_in[5];
  const float* conv_w = (const float*)d_in[6];
  const float* conv_b = (const float*)d_in[7];
  const float* w_xprj = (const float*)d_in[8];
  const float* w_dt   = (const float*)d_in[9];
  const float* b_dt   = (const float*)d_in[10];
  const float* A_log  = (const float*)d_in[11];
  const float* Dp     = (const float*)d_in[12];
  const float* w_out  = (const float*)d_in[13];
  const float* ln2_g  = (const float*)d_in[14];
  const float* ln2_b  = (const float*)d_in[15];
  const float* fc1_w  = (const float*)d_in[16];
  const float* bn1_s  = (const float*)d_in[17];
  const float* bn1_b  = (const float*)d_in[18];
  const float* Wr     = (const float*)d_in[19];
  const float* Wi     = (const float*)d_in[20];
  const float* rb     = (const float*)d_in[21];
  const float* ib     = (const float*)d_in[22];
  const float* fc2_w  = (const float*)d_in[23];
  const float* bn2_s  = (const float*)d_in[24];
  const float* bn2_b  = (const float*)d_in[25];

  float* ws = (float*)d_ws;
  unsigned short* hb   = (unsigned short*)(ws + OFF_HB);   // reused as h2b
  float* xr     = ws + OFF_XRF;
  float* xc_t   = ws + OFF_XCT;
  float* res_t  = ws + OFF_REST;
  float* yf_t   = ws + OFF_YFT;
  float* x2     = ws + OFF_X2;
  unsigned short* xcb  = (unsigned short*)(ws + OFF_XCB);
  unsigned short* xdbl = (unsigned short*)(ws + OFF_XDBL);
  unsigned short* PK   = (unsigned short*)(ws + OFF_YFT);
  unsigned short* ftb  = (unsigned short*)(ws + OFF_FTB);
  unsigned short* RFb  = (unsigned short*)(ws + OFF_RF);
  unsigned short* IFb  = (unsigned short*)(ws + OFF_IF);
  unsigned short* ffb  = (unsigned short*)(ws + OFF_FFB);
  unsigned short* winT = (unsigned short*)(ws + OFF_WINT);
  unsigned short* Wrt  = (unsigned short*)(ws + OFF_WRT);
  unsigned short* Wit  = (unsigned short*)(ws + OFF_WIT);
  unsigned short* wxpT = (unsigned short*)(ws + OFF_WXPT);
  unsigned short* woT  = (unsigned short*)(ws + OFF_WOT);
  unsigned short* fc1T = (unsigned short*)(ws + OFF_FC1T);
  unsigned short* fc2T = (unsigned short*)(ws + OFF_FC2T);
  unsigned short* Cfb  = (unsigned short*)(ws + OFF_CF);
  unsigned short* Sfb  = (unsigned short*)(ws + OFF_SF);
  unsigned short* Cib  = (unsigned short*)(ws + OFF_CI);
  unsigned short* h2b  = hb;
  float* out = (float*)d_out;

  // 1: all weight packs + trig matrices + first double-LN in one launch
  setup_kernel<<<1032, 256, 0, stream>>>(w_in, Wr, Wi, w_xprj, w_out, fc1_w, fc2_w,
                                         winT, Wrt, Wit, wxpT, woT, fc1T, fc2T,
                                         Cfb, Sfb, Cib,
                                         x, hb, ln1_g, ln1_b, mln_g, mln_b);
  // 2: xr = hb @ w_in (f32)
  gemm_mfma<<<dim3(16, 36), 256, 0, stream>>>(hb, winT, xr, NWIN, NTOK, NWIN, NC,
                                              0, 0, nullptr, nullptr, nullptr, 0);
  // 3: xc_t f32 + xcb bf16 + res_t
  convT_kernel<<<dim3(8, 36, 2), 256, 0, stream>>>(xr, conv_w, conv_b, xc_t, res_t, xcb);
  // 4: xdbl = bf16((xcb @ w_xproj)^T), token-permuted [112][2304]
  gemm_mfma<<<dim3(2, 36), 256, 0, stream>>>(xcb, wxpT, xdbl, NTOK, NTOK, NXD, NDIN,
                                             0, 14, nullptr, nullptr, nullptr, 0);
  // 5: scan (fused delta, bf16 B/C)
  scan7_kernel<<<NB * NDIN, 256, 0, stream>>>(xc_t, xdbl, w_dt, b_dt, A_log, Dp, res_t, yf_t);
  // 6: x2 = x + yf @ w_out  (A = yf_t f32 K-major, staged+converted in-kernel)
  gemm_mfma<<<dim3(4, 36), 256, 0, stream>>>((const unsigned short*)yf_t, woT, x2, NC,
                                             NTOK, NC, NDIN, 2, 32, nullptr, nullptr, x, NC);
  // 7: h2b = bf16(LN(x2))
  ln_kernel<<<NTOK, 64, 0, stream>>>(x2, h2b, ln2_g, ln2_b);
  // 8: ftb = bf16(relu(h2b@fc1 * s + b))^T [512][2304]
  gemm_mfma<<<dim3(8, 36), 256, 0, stream>>>(h2b, fc1T, ftb, NTOK, NTOK, NDIN, NC,
                                             3, 6, bn1_s, bn1_b, nullptr, 0);
  // 9-11: rfft / mix / irfft on MFMA (idft masks PK pad lanes in-register)
  dftf_mfma_kernel<<<dim3(8, 5, NB), 256, 0, stream>>>(Cfb, Sfb, ftb, RFb, IFb);
  mix_mfma_kernel<<<dim3(19, 8), 256, 0, stream>>>(RFb, IFb, Wrt, Wit, rb, ib, PK);
  idft_mfma_kernel<<<dim3(8, 9, NB), 256, 0, stream>>>(Cib, PK, ffb);
  // 12: out = x2 + ffb @ fc2 * s + b
  gemm_mfma<<<dim3(4, 36), 256, 0, stream>>>(ffb, fc2T, out, NC, NTOK, NC, NDIN,
                                             4, 0, bn2_s, bn2_b, x2, NC);
}